// Round 17
// baseline (59.192 us; speedup 1.0000x reference)
//
#include <hip/hip_runtime.h>

#define NB 2
#define NN 1024
#define NK 64
#define NG 64
#define NF 128
#define NH 4
#define NO 128
#define PITCH 132   // ys pitch in k_projprep (bank-spread)

typedef unsigned short ushort_t;
typedef __attribute__((ext_vector_type(8))) short short8v;
typedef __attribute__((ext_vector_type(4))) float f32x4;

union FragU { uint4 u4; short8v s8; };

__device__ __forceinline__ float bf2f(ushort_t u) {
    union { unsigned int i; float f; } v; v.i = ((unsigned int)u) << 16; return v.f;
}
__device__ __forceinline__ ushort_t f2bf(float f) {
    unsigned int u = __float_as_uint(f);
    unsigned int r = 0x7fffu + ((u >> 16) & 1u);
    return (ushort_t)((u + r) >> 16);
}
// shifted softplus via hardware exp2/log2:
// ssp(x) = max(x,0) + ln2*log2(1 + 2^(-|x|*log2e)) - ln2; abs err ~1e-7.
__device__ __forceinline__ float sspf(float x) {
    const float u = __builtin_amdgcn_exp2f(-fabsf(x) * 1.44269504088896341f);
    return fmaxf(x, 0.f) + fmaf(0.69314718055994531f,
                                __builtin_amdgcn_logf(1.f + u),
                                -0.69314718055994531f);
}

// ---------------------------------------------------------------------------
// Kernel 1 (merged): blocks [0,256) = y-projection + attention dots;
// blocks [256,284) = weight prep (wf1/wf2 frag tables + w_out transpose).
// frag table layout: table[(fi*64+lane)*8+j], fi = ks*8+nf; element j maps to
// k = ks*32 + ((lane>>4)&3)*4 + (j&3) + 16*(j>>2), n = nf*16 + (lane&15).
// ---------------------------------------------------------------------------
__global__ __launch_bounds__(256) void k_projprep(
    const float* __restrict__ x,       // [B][N][F]
    const float* __restrict__ w_in2f,  // [H][F][F]
    const float* __restrict__ w_att,   // [H][2F]
    const float* __restrict__ wf1, const float* __restrict__ wf2,
    const float* __restrict__ w_out,
    ushort_t* __restrict__ y,          // [B][H][N][F] bf16
    float* __restrict__ a_c,           // [B][H][N]
    float* __restrict__ a_n,           // [B][H][N]
    ushort_t* __restrict__ wf1f, ushort_t* __restrict__ wf2f,
    float* __restrict__ w_outT)
{
    const int t = threadIdx.x;
    __shared__ float xs[8][NF];
    __shared__ float ys[32][PITCH];

    if (blockIdx.x >= 256) {
        // ---- prep path ----
        int s = (blockIdx.x - 256) * 256 + t;
        if (s >= 7168) return;
        if (s >= 3072) {
            const int s2 = s - 3072;           // [0,4096)
            const int o = s2 >> 5, fb = s2 & 31;
            #pragma unroll
            for (int j = 0; j < 4; ++j)
                w_outT[(size_t)o * NF + fb * 4 + j] = w_out[(size_t)(fb * 4 + j) * NO + o];
            return;
        }
        const float* W; ushort_t* out; int loOff;
        if (s < 1024) { W = wf1; out = wf1f; loOff = 8192; }
        else          { s -= 1024; W = wf2; out = wf2f; loOff = 16384; }
        const int fi = s >> 6, lane = s & 63;
        const int ks = fi >> 3, nf = fi & 7;
        const int n = nf * 16 + (lane & 15);
        const int kb = ks * 32 + ((lane >> 4) & 3) * 4;
        #pragma unroll
        for (int j = 0; j < 8; ++j) {
            const int k = kb + (j & 3) + ((j >> 2) << 4);
            const float v = W[(size_t)k * NF + n];
            const ushort_t hb = f2bf(v);
            out[(size_t)(fi * 64 + lane) * 8 + j] = hb;
            out[(size_t)loOff + (fi * 64 + lane) * 8 + j] = f2bf(v - bf2f(hb));
        }
        return;
    }

    // ---- projection path ----
    const int bn0 = blockIdx.x * 8;
    {
        const float4* src = (const float4*)(x + (size_t)bn0 * NF);
        float4* dst = (float4*)(&xs[0][0]);
        dst[t] = src[t];
    }
    __syncthreads();

    const int hp = t >> 7;
    const int f0 = t & 127;
    const int h0 = hp, h1 = hp + 2;
    const float* w0 = w_in2f + (size_t)h0 * NF * NF + f0;
    const float* w1 = w_in2f + (size_t)h1 * NF * NF + f0;
    float acc0[8], acc1[8];
    #pragma unroll
    for (int n = 0; n < 8; ++n) { acc0[n] = 0.f; acc1[n] = 0.f; }

    for (int i0 = 0; i0 < NF; i0 += 4) {
        float4 xv[8];
        #pragma unroll
        for (int n = 0; n < 8; ++n) xv[n] = *(const float4*)&xs[n][i0];
        #pragma unroll
        for (int ii = 0; ii < 4; ++ii) {
            const float wa = w0[(size_t)(i0 + ii) * NF];
            const float wb = w1[(size_t)(i0 + ii) * NF];
            #pragma unroll
            for (int n = 0; n < 8; ++n) {
                const float xi = (&xv[n].x)[ii];
                acc0[n] = fmaf(xi, wa, acc0[n]);
                acc1[n] = fmaf(xi, wb, acc1[n]);
            }
        }
    }
    #pragma unroll
    for (int n = 0; n < 8; ++n) {
        const int bn = bn0 + n;
        const int b = bn >> 10, nn = bn & (NN - 1);
        y[((size_t)(b * NH + h0) * NN + nn) * NF + f0] = f2bf(acc0[n]);
        y[((size_t)(b * NH + h1) * NN + nn) * NF + f0] = f2bf(acc1[n]);
        ys[n * 4 + h0][f0] = acc0[n];
        ys[n * 4 + h1][f0] = acc1[n];
    }
    __syncthreads();

    {
        const int hn = t >> 3, q = t & 7;
        const int h = hn & 3, n = hn >> 2;
        float pc = 0.f, pn = 0.f;
        #pragma unroll
        for (int j = 0; j < 16; ++j) {
            const int f = q + 8 * j;
            const float yv = ys[n * 4 + h][f];
            pc = fmaf(yv, w_att[h * 2 * NF + f], pc);
            pn = fmaf(yv, w_att[h * 2 * NF + NF + f], pn);
        }
        #pragma unroll
        for (int off = 1; off < 8; off <<= 1) {
            pc += __shfl_xor(pc, off, 8);
            pn += __shfl_xor(pn, off, 8);
        }
        if (q == 0) {
            const int bn = bn0 + n;
            const int b = bn >> 10, nn = bn & (NN - 1);
            a_c[(size_t)(b * NH + h) * NN + nn] = pc;
            a_n[(size_t)(b * NH + h) * NN + nn] = pn;
        }
    }
}

// ---------------------------------------------------------------------------
// Kernel 2 (round 17): round-12 dataflow, restructured for 8 blocks/CU
// (one scheduling round, no tail):
//   - A1/A2 split into two row-half passes (acc[2][2] = 16 AGPRs, not 32)
//     Overlay safety (pitch 132 = 264 B/row, fij pitch 68 = 136 B/row):
//       A1 epi0 writes W1 rows 32-63 = bytes [8448,16896) — pass-1 reads
//       fij rows 0-31 = [0,4352), disjoint. W2 row-block mf depends only on
//       W1 row-block mf (block-diagonal), so in-place per pass after barrier.
//   - aggp [4][128] via intra-wave shfl_xor(32) pair-combine; aggc overlays
//     dead alpha -> LDS 20224 <= 20480 (8 blocks/CU)
//   - launch_bounds(256,8): est. peak live ~54-59 unified regs <= 64 cap.
//     TRIPWIRE: WRITE_SIZE >> 1 MB = spill = revert to round-16 source.
// LDS map (20224 B):
//   [0     ..16896)  fij [64][68] -> W1 [64][132] -> W2 [64][132] (per-pass)
//   [16896 ..18944)  aggp [4][128] f32
//   [18944 ..19968)  alpha [4][64] f32 -> aggc [128] f32 overlay after bar8
//   [19968 ..20224)  nbs [64] int
// ---------------------------------------------------------------------------
__global__ __launch_bounds__(256, 8) void k_main(
    const int*      __restrict__ neighbors, // [B][N][K]
    const float*    __restrict__ pmask,     // [B][N][K]
    const float*    __restrict__ f_ij,      // [B][N][K][G]
    const float*    __restrict__ bf1,       // [F]
    const float*    __restrict__ bf2v,      // [F]
    const float*    __restrict__ w_outT,    // [O][F] transposed
    const float*    __restrict__ b_out,     // [O]
    const ushort_t* __restrict__ y,         // [B][H][N][F] bf16
    const float*    __restrict__ a_c,       // [B][H][N]
    const float*    __restrict__ a_n,       // [B][H][N]
    const ushort_t* __restrict__ wf1f,      // frag table hi/lo
    const ushort_t* __restrict__ wf2f,      // frag table hi
    float*          __restrict__ outp)      // [B][N][O]
{
    const int bn = blockIdx.x;
    const int b = bn >> 10, n_ = bn & (NN - 1);
    const int t = threadIdx.x;

    __shared__ __align__(16) char smem[20224];
    ushort_t* fijs = (ushort_t*)(smem);           // [64][68] bf16 (rounded)
    ushort_t* W1   = (ushort_t*)(smem);           // [64][132] per-pass overlay
    ushort_t* W2   = (ushort_t*)(smem);           // [64][132] per-pass overlay
    float*    aggp = (float*)(smem + 16896);      // [4][128]
    float*    alpha = (float*)(smem + 18944);     // [4][64]
    float*    aggc = (float*)(smem + 18944);      // overlay (alpha dead) after bar8
    int*      nbs   = (int*)(smem + 19968);       // [64]

    const int wave = t >> 6, lane = t & 63;
    const int lrow = lane & 15;          // A-row / B-col / C-col within frag
    const int lq   = (lane >> 4) & 3;    // quarter
    const int wb   = wave * 32;          // this wave's N-column base

    // ---- stage f_ij (fp32 global, coalesced) -> rounded bf16 LDS ----
    {
        const float4* src = (const float4*)(f_ij + (size_t)bn * NK * NG);
        #pragma unroll
        for (int i = 0; i < 4; ++i) {
            const int e4 = i * 256 + t;
            const float4 v = src[e4];
            const int e = e4 * 4;
            const int row = e >> 6, col = e & 63;
            uint2 ph;
            ph.x = (unsigned)f2bf(v.x) | ((unsigned)f2bf(v.y) << 16);
            ph.y = (unsigned)f2bf(v.z) | ((unsigned)f2bf(v.w) << 16);
            *(uint2*)&fijs[row * 68 + col] = ph;
        }
    }
    if (t < NK) nbs[t] = neighbors[(size_t)bn * NK + t];
    __syncthreads();                                            // bar1

    f32x4 acc[2][2];

    auto a1_compute = [&](int mfb) {
        #pragma unroll
        for (int mf2 = 0; mf2 < 2; ++mf2)
            #pragma unroll
            for (int nf2 = 0; nf2 < 2; ++nf2) acc[mf2][nf2] = (f32x4)0.f;
        #pragma unroll
        for (int ks = 0; ks < 2; ++ks) {
            FragU b1h[2], b1l[2];
            #pragma unroll
            for (int nf2 = 0; nf2 < 2; ++nf2) {
                const int fi = ks * 8 + wave * 2 + nf2;
                b1h[nf2].u4 = *((const uint4*)wf1f + fi * 64 + lane);
                b1l[nf2].u4 = *((const uint4*)(wf1f + 8192) + fi * 64 + lane);
            }
            const int cb = ks * 32 + lq * 4;
            #pragma unroll
            for (int mf2 = 0; mf2 < 2; ++mf2) {
                const int row = (mfb + mf2) * 16 + lrow;
                FragU ah;
                {
                    const uint2 p0 = *(const uint2*)&fijs[row * 68 + cb];
                    const uint2 p1 = *(const uint2*)&fijs[row * 68 + cb + 16];
                    uint4 q; q.x = p0.x; q.y = p0.y; q.z = p1.x; q.w = p1.y; ah.u4 = q;
                }
                #pragma unroll
                for (int nf2 = 0; nf2 < 2; ++nf2) {
                    acc[mf2][nf2] = __builtin_amdgcn_mfma_f32_16x16x32_bf16(ah.s8, b1h[nf2].s8, acc[mf2][nf2], 0, 0, 0);
                    acc[mf2][nf2] = __builtin_amdgcn_mfma_f32_16x16x32_bf16(ah.s8, b1l[nf2].s8, acc[mf2][nf2], 0, 0, 0);
                }
            }
        }
    };
    auto a1_epi = [&](int mfb) {
        const float bia[2] = { bf1[wb + lrow], bf1[wb + 16 + lrow] };
        #pragma unroll
        for (int mf2 = 0; mf2 < 2; ++mf2)
            #pragma unroll
            for (int nf2 = 0; nf2 < 2; ++nf2) {
                const int col = wb + nf2 * 16 + lrow;
                #pragma unroll
                for (int r = 0; r < 4; ++r) {
                    const int row = (mfb + mf2) * 16 + lq * 4 + r;
                    W1[row * 132 + col] = f2bf(sspf(acc[mf2][nf2][r] + bia[nf2]));
                }
            }
    };
    auto a2_compute = [&](int mfb) {
        #pragma unroll
        for (int mf2 = 0; mf2 < 2; ++mf2)
            #pragma unroll
            for (int nf2 = 0; nf2 < 2; ++nf2) acc[mf2][nf2] = (f32x4)0.f;
        for (int ks = 0; ks < 4; ++ks) {
            FragU b2h[2];
            #pragma unroll
            for (int nf2 = 0; nf2 < 2; ++nf2) {
                const int fi = ks * 8 + wave * 2 + nf2;
                b2h[nf2].u4 = *((const uint4*)wf2f + fi * 64 + lane);
            }
            const int cb = ks * 32 + lq * 4;
            #pragma unroll
            for (int mf2 = 0; mf2 < 2; ++mf2) {
                const int row = (mfb + mf2) * 16 + lrow;
                FragU ah;
                {
                    const uint2 p0 = *(const uint2*)&W1[row * 132 + cb];
                    const uint2 p1 = *(const uint2*)&W1[row * 132 + cb + 16];
                    uint4 q; q.x = p0.x; q.y = p0.y; q.z = p1.x; q.w = p1.y; ah.u4 = q;
                }
                #pragma unroll
                for (int nf2 = 0; nf2 < 2; ++nf2)
                    acc[mf2][nf2] = __builtin_amdgcn_mfma_f32_16x16x32_bf16(ah.s8, b2h[nf2].s8, acc[mf2][nf2], 0, 0, 0);
            }
        }
    };
    auto a2_epi = [&](int mfb) {
        const float bia[2] = { bf2v[wb + lrow], bf2v[wb + 16 + lrow] };
        #pragma unroll
        for (int mf2 = 0; mf2 < 2; ++mf2)
            #pragma unroll
            for (int nf2 = 0; nf2 < 2; ++nf2) {
                const int col = wb + nf2 * 16 + lrow;
                #pragma unroll
                for (int r = 0; r < 4; ++r) {
                    const int row = (mfb + mf2) * 16 + lq * 4 + r;
                    W2[row * 132 + col] = f2bf(acc[mf2][nf2][r] + bia[nf2]);
                }
            }
    };

    // ---- Phase A1 (two row-half passes; overlay-safe byte ranges) ----
    a1_compute(2);                      // reads fij rows 32-63
    __syncthreads();                    // bar2 (fij[8448:8704) about to be clobbered)
    a1_epi(2);                          // writes W1 rows 32-63 = [8448,16896)
    a1_compute(0);                      // reads fij rows 0-31 = [0,4352), disjoint
    __syncthreads();                    // bar3 (fij[0:4352) reads done)
    a1_epi(0);                          // writes W1 rows 0-31 = [0,8448)
    __syncthreads();                    // bar4 (W1 complete)

    // ---- Phase A2 (block-diagonal in row-blocks; in-place W1->W2) ----
    a2_compute(2);                      // reads W1 rows 32-63
    __syncthreads();                    // bar5 (those reads done before overwrite)
    a2_epi(2);                          // writes W2 rows 32-63 (same bytes)
    a2_compute(0);                      // reads W1 rows 0-31, disjoint from epi(2)

    // ---- Phase B: attention softmax (wave == head), mask folded in ----
    {
        const float av = a_c[(size_t)(b * NH + wave) * NN + n_]
                       + a_n[(size_t)(b * NH + wave) * NN + nbs[lane]];
        const float att = sspf(av);
        float m = att;
        #pragma unroll
        for (int off = 32; off > 0; off >>= 1) m = fmaxf(m, __shfl_xor(m, off, 64));
        const float e = __builtin_amdgcn_exp2f((att - m) * 1.44269504088896341f);
        float s = e;
        #pragma unroll
        for (int off = 32; off > 0; off >>= 1) s += __shfl_xor(s, off, 64);
        alpha[wave * 64 + lane] = (e / s) * pmask[(size_t)bn * NK + lane];
    }
    __syncthreads();                    // bar6 (W1[0:8448) reads + alpha done)
    a2_epi(0);                          // writes W2 rows 0-31
    __syncthreads();                    // bar7 (W2 + alpha ready)

    // ---- Phase C: agg[f] = (1/H) sum_k W2[k][f] * sum_h alpha[h][k]*y[b,h,nb,f] ----
    {
        const int fq = (t & 31) * 4;
        const int kg = t >> 5;          // 0..7
        float4 accv; accv.x = accv.y = accv.z = accv.w = 0.f;
        const ushort_t* yb = y + (size_t)b * NH * NN * NF;
        #pragma unroll 2
        for (int kk = 0; kk < 8; ++kk) {
            const int k = kg * 8 + kk;
            const int nb = nbs[k];
            const ushort_t* yp = yb + (size_t)nb * NF + fq;
            const uint2 u0 = *(const uint2*)(yp);
            const uint2 u1 = *(const uint2*)(yp + (size_t)NN * NF);
            const uint2 u2 = *(const uint2*)(yp + 2 * (size_t)NN * NF);
            const uint2 u3 = *(const uint2*)(yp + 3 * (size_t)NN * NF);
            const float a0 = alpha[0 * 64 + k], a1 = alpha[1 * 64 + k];
            const float a2 = alpha[2 * 64 + k], a3 = alpha[3 * 64 + k];
            float4 s;
            s.x = fmaf(a3, bf2f((ushort_t)(u3.x & 0xffffu)),
                  fmaf(a2, bf2f((ushort_t)(u2.x & 0xffffu)),
                  fmaf(a1, bf2f((ushort_t)(u1.x & 0xffffu)),
                       a0 * bf2f((ushort_t)(u0.x & 0xffffu)))));
            s.y = fmaf(a3, bf2f((ushort_t)(u3.x >> 16)),
                  fmaf(a2, bf2f((ushort_t)(u2.x >> 16)),
                  fmaf(a1, bf2f((ushort_t)(u1.x >> 16)),
                       a0 * bf2f((ushort_t)(u0.x >> 16)))));
            s.z = fmaf(a3, bf2f((ushort_t)(u3.y & 0xffffu)),
                  fmaf(a2, bf2f((ushort_t)(u2.y & 0xffffu)),
                  fmaf(a1, bf2f((ushort_t)(u1.y & 0xffffu)),
                       a0 * bf2f((ushort_t)(u0.y & 0xffffu)))));
            s.w = fmaf(a3, bf2f((ushort_t)(u3.y >> 16)),
                  fmaf(a2, bf2f((ushort_t)(u2.y >> 16)),
                  fmaf(a1, bf2f((ushort_t)(u1.y >> 16)),
                       a0 * bf2f((ushort_t)(u0.y >> 16)))));
            const uint2 wv = *(const uint2*)&W2[k * 132 + fq];
            accv.x = fmaf(bf2f((ushort_t)(wv.x & 0xffffu)), s.x, accv.x);
            accv.y = fmaf(bf2f((ushort_t)(wv.x >> 16)),     s.y, accv.y);
            accv.z = fmaf(bf2f((ushort_t)(wv.y & 0xffffu)), s.z, accv.z);
            accv.w = fmaf(bf2f((ushort_t)(wv.y >> 16)),     s.w, accv.w);
        }
        // pair-combine kg and kg^1 within the wave (lanes l and l+32 share fq)
        accv.x += __shfl_xor(accv.x, 32, 64);
        accv.y += __shfl_xor(accv.y, 32, 64);
        accv.z += __shfl_xor(accv.z, 32, 64);
        accv.w += __shfl_xor(accv.w, 32, 64);
        if (lane < 32) *(float4*)&aggp[wave * 128 + fq] = accv;
    }
    __syncthreads();                    // bar8 (aggp written; alpha dead)
    if (t < NF) {
        aggc[t] = (aggp[t] + aggp[128 + t] + aggp[256 + t] + aggp[384 + t]) * 0.25f;
    }
    __syncthreads();                    // bar9

    // ---- Phase D: out = ssp(agg @ w_outT + b_out), vectorized loads ----
    if (t < NO) {
        float z = b_out[t];
        const float4* wr = (const float4*)(w_outT + (size_t)t * NF);
        #pragma unroll 8
        for (int q = 0; q < NF / 4; ++q) {
            const float4 w = wr[q];
            const float4 a = *(const float4*)&aggc[q * 4];
            z = fmaf(a.x, w.x, fmaf(a.y, w.y, fmaf(a.z, w.z, fmaf(a.w, w.w, z))));
        }
        outp[(size_t)bn * NO + t] = sspf(z);
    }
}

extern "C" void kernel_launch(void* const* d_in, const int* in_sizes, int n_in,
                              void* d_out, int out_size, void* d_ws, size_t ws_size,
                              hipStream_t stream) {
    const float* x      = (const float*)d_in[0];
    // d_in[1] = r_ij (unused by reference)
    const int*   nbr    = (const int*)d_in[2];
    const float* pmask  = (const float*)d_in[3];
    const float* f_ij   = (const float*)d_in[4];
    const float* w_in2f = (const float*)d_in[5];
    const float* w_att  = (const float*)d_in[6];
    const float* wf1    = (const float*)d_in[7];
    const float* bf1    = (const float*)d_in[8];
    const float* wf2    = (const float*)d_in[9];
    const float* bf2v   = (const float*)d_in[10];
    const float* w_out  = (const float*)d_in[11];
    const float* b_out  = (const float*)d_in[12];

    // ws layout (total ~2.22 MB):
    //   yb16  [B][H][N][F] bf16 : 2 MB
    //   a_c   [B][H][N] f32     : 32 KB
    //   a_n   [B][H][N] f32     : 32 KB
    //   wf1f  hi+lo bf16 tables : 32 KB
    //   wf2f  hi+lo bf16 tables : 64 KB
    //   w_outT [O][F] f32       : 64 KB
    ushort_t* yb16  = (ushort_t*)d_ws;
    float*    a_c   = (float*)(yb16 + (size_t)NB * NH * NN * NF);
    float*    a_n   = a_c + (size_t)NB * NH * NN;
    ushort_t* wf1f  = (ushort_t*)(a_n + (size_t)NB * NH * NN);
    ushort_t* wf2f  = wf1f + 16384;
    float*    w_outT = (float*)(wf2f + 32768);

    float* outp = (float*)d_out;

    k_projprep<<<NB * NN / 8 + 28, 256, 0, stream>>>(
        x, w_in2f, w_att, wf1, wf2, w_out, yb16, a_c, a_n, wf1f, wf2f, w_outT);
    k_main<<<NB * NN, 256, 0, stream>>>(nbr, pmask, f_ij, bf1, bf2v,
                                        w_outT, b_out, yb16, a_c, a_n, wf1f, wf2f, outp);
}

// Round 18
// 52.244 us; speedup vs baseline: 1.1330x; 1.1330x over previous
//
#include <hip/hip_runtime.h>

#define NB 2
#define NN 1024
#define NK 64
#define NG 64
#define NF 128
#define NH 4
#define NO 128

typedef unsigned short ushort_t;
typedef __attribute__((ext_vector_type(8))) short short8v;
typedef __attribute__((ext_vector_type(4))) float f32x4;

union FragU { uint4 u4; short8v s8; };

__device__ __forceinline__ float bf2f(ushort_t u) {
    union { unsigned int i; float f; } v; v.i = ((unsigned int)u) << 16; return v.f;
}
__device__ __forceinline__ ushort_t f2bf(float f) {
    unsigned int u = __float_as_uint(f);
    unsigned int r = 0x7fffu + ((u >> 16) & 1u);
    return (ushort_t)((u + r) >> 16);
}
// shifted softplus via hardware exp2/log2:
// ssp(x) = max(x,0) + ln2*log2(1 + 2^(-|x|*log2e)) - ln2; abs err ~1e-7.
__device__ __forceinline__ float sspf(float x) {
    const float u = __builtin_amdgcn_exp2f(-fabsf(x) * 1.44269504088896341f);
    return fmaxf(x, 0.f) + fmaf(0.69314718055994531f,
                                __builtin_amdgcn_logf(1.f + u),
                                -0.69314718055994531f);
}

// ---------------------------------------------------------------------------
// Kernel 1 (round 18): head-split projection for 4x parallelism.
// blocks [0,1024): proj — block (g,h) = (idx>>2, idx&3) computes y rows
//   [8g,8g+8) for head h (weights/block 64 KB; total L2 weight traffic
//   unchanged at 64 MB, but 4 blocks/CU instead of 1 -> 512 FMA/thread).
// blocks [1024,1052): weight prep (wf1/wf2 frag tables + w_out transpose).
// frag table layout: table[(fi*64+lane)*8+j], fi = ks*8+nf; element j maps to
// k = ks*32 + ((lane>>4)&3)*4 + (j&3) + 16*(j>>2), n = nf*16 + (lane&15).
// ---------------------------------------------------------------------------
__global__ __launch_bounds__(256) void k_projprep(
    const float* __restrict__ x,       // [B][N][F]
    const float* __restrict__ w_in2f,  // [H][F][F]
    const float* __restrict__ w_att,   // [H][2F]
    const float* __restrict__ wf1, const float* __restrict__ wf2,
    const float* __restrict__ w_out,
    ushort_t* __restrict__ y,          // [B][H][N][F] bf16
    float* __restrict__ a_c,           // [B][H][N]
    float* __restrict__ a_n,           // [B][H][N]
    ushort_t* __restrict__ wf1f, ushort_t* __restrict__ wf2f,
    float* __restrict__ w_outT)
{
    const int t = threadIdx.x;
    __shared__ float xs[8][NF];        // 4 KB
    __shared__ float ys[8][NF];        // 4 KB (stride-1 dot reads, no conflict)

    if (blockIdx.x >= 1024) {
        // ---- prep path ----
        int s = (blockIdx.x - 1024) * 256 + t;
        if (s >= 7168) return;
        if (s >= 3072) {
            const int s2 = s - 3072;           // [0,4096)
            const int o = s2 >> 5, fb = s2 & 31;
            #pragma unroll
            for (int j = 0; j < 4; ++j)
                w_outT[(size_t)o * NF + fb * 4 + j] = w_out[(size_t)(fb * 4 + j) * NO + o];
            return;
        }
        const float* W; ushort_t* out; int loOff;
        if (s < 1024) { W = wf1; out = wf1f; loOff = 8192; }
        else          { s -= 1024; W = wf2; out = wf2f; loOff = 16384; }
        const int fi = s >> 6, lane = s & 63;
        const int ks = fi >> 3, nf = fi & 7;
        const int n = nf * 16 + (lane & 15);
        const int kb = ks * 32 + ((lane >> 4) & 3) * 4;
        #pragma unroll
        for (int j = 0; j < 8; ++j) {
            const int k = kb + (j & 3) + ((j >> 2) << 4);
            const float v = W[(size_t)k * NF + n];
            const ushort_t hb = f2bf(v);
            out[(size_t)(fi * 64 + lane) * 8 + j] = hb;
            out[(size_t)loOff + (fi * 64 + lane) * 8 + j] = f2bf(v - bf2f(hb));
        }
        return;
    }

    // ---- projection path: 8 rows x 1 head per block ----
    const int g  = blockIdx.x >> 2;
    const int h  = blockIdx.x & 3;
    const int bn0 = g * 8;
    {
        const float4* src = (const float4*)(x + (size_t)bn0 * NF);
        float4* dst = (float4*)(&xs[0][0]);
        dst[t] = src[t];               // 256 float4 = 8 rows
    }
    __syncthreads();

    const int f0 = t & 127;
    const int rp = t >> 7;             // 0..1 -> rows [4rp, 4rp+4)
    const float* wp = w_in2f + (size_t)h * NF * NF + f0;
    float acc[4];
    #pragma unroll
    for (int j = 0; j < 4; ++j) acc[j] = 0.f;

    for (int i0 = 0; i0 < NF; i0 += 4) {
        float4 xv[4];
        #pragma unroll
        for (int j = 0; j < 4; ++j) xv[j] = *(const float4*)&xs[rp * 4 + j][i0];
        #pragma unroll
        for (int ii = 0; ii < 4; ++ii) {
            const float w = wp[(size_t)(i0 + ii) * NF];
            #pragma unroll
            for (int j = 0; j < 4; ++j)
                acc[j] = fmaf((&xv[j].x)[ii], w, acc[j]);
        }
    }
    #pragma unroll
    for (int j = 0; j < 4; ++j) {
        const int bn = bn0 + rp * 4 + j;
        const int b = bn >> 10, nn = bn & (NN - 1);
        y[((size_t)(b * NH + h) * NN + nn) * NF + f0] = f2bf(acc[j]);
        ys[rp * 4 + j][f0] = acc[j];
    }
    __syncthreads();

    // attention dots: row r handled by 32 lanes, stride-1 f reads
    {
        const int r = t >> 5, q = t & 31;
        float pc = 0.f, pn = 0.f;
        #pragma unroll
        for (int j = 0; j < 4; ++j) {
            const int f = q + 32 * j;
            const float yv = ys[r][f];
            pc = fmaf(yv, w_att[h * 2 * NF + f], pc);
            pn = fmaf(yv, w_att[h * 2 * NF + NF + f], pn);
        }
        #pragma unroll
        for (int off = 1; off < 32; off <<= 1) {
            pc += __shfl_xor(pc, off, 32);
            pn += __shfl_xor(pn, off, 32);
        }
        if (q == 0) {
            const int bn = bn0 + r;
            const int b = bn >> 10, nn = bn & (NN - 1);
            a_c[(size_t)(b * NH + h) * NN + nn] = pc;
            a_n[(size_t)(b * NH + h) * NN + nn] = pn;
        }
    }
}

// ---------------------------------------------------------------------------
// Kernel 2 (round-16 version verbatim — measured session best, 56.5 us x2):
//   - fij staged as rounded bf16 (no lo): A1 = 2-term MFMA (wf1 hi+lo)
//   - A2 = 1-term MFMA (wf2 hi); W2 stored bf16
//   - LDS liveness chain fij -> W1 -> W2 in one region, 7 barriers
//   - launch_bounds(256,6): 40 VGPR + 32 AGPR = 72 <= 85 cap, zero spill
// LDS map (22784 B -> 6 blocks/CU by reg tier):
//   R1 [0     ..16896)  fij [64][68] bf16 -> W1 [64][132] -> W2 [64][132]
//   R2 [16896 ..20992)  aggp [8][128] f32
//      [20992 ..21504)  aggc [128] f32
//   R3 [21504 ..22528)  alpha [4][64] f32
//      [22528 ..22784)  nbs [64] int
// ---------------------------------------------------------------------------
__global__ __launch_bounds__(256, 6) void k_main(
    const int*      __restrict__ neighbors, // [B][N][K]
    const float*    __restrict__ pmask,     // [B][N][K]
    const float*    __restrict__ f_ij,      // [B][N][K][G]
    const float*    __restrict__ bf1,       // [F]
    const float*    __restrict__ bf2v,      // [F]
    const float*    __restrict__ w_outT,    // [O][F] transposed
    const float*    __restrict__ b_out,     // [O]
    const ushort_t* __restrict__ y,         // [B][H][N][F] bf16
    const float*    __restrict__ a_c,       // [B][H][N]
    const float*    __restrict__ a_n,       // [B][H][N]
    const ushort_t* __restrict__ wf1f,      // frag table hi/lo
    const ushort_t* __restrict__ wf2f,      // frag table hi
    float*          __restrict__ outp)      // [B][N][O]
{
    const int bn = blockIdx.x;
    const int b = bn >> 10, n_ = bn & (NN - 1);
    const int t = threadIdx.x;

    __shared__ __align__(16) char smem[22784];
    ushort_t* fijs = (ushort_t*)(smem);           // [64][68] bf16 (rounded)
    ushort_t* W1   = (ushort_t*)(smem);           // [64][132] overlay (after bar2)
    ushort_t* W2   = (ushort_t*)(smem);           // [64][132] overlay (after bar4)
    float*    aggp = (float*)(smem + 16896);      // [8][128]
    float*    aggc = (float*)(smem + 20992);      // [128]
    float*    alpha = (float*)(smem + 21504);     // [4][64]
    int*      nbs   = (int*)(smem + 22528);       // [64]

    const int wave = t >> 6, lane = t & 63;
    const int lrow = lane & 15;          // A-row / B-col / C-col within frag
    const int lq   = (lane >> 4) & 3;    // quarter
    const int wb   = wave * 32;          // this wave's N-column base

    // ---- stage f_ij (fp32 global, coalesced) -> rounded bf16 LDS ----
    {
        const float4* src = (const float4*)(f_ij + (size_t)bn * NK * NG);
        #pragma unroll
        for (int i = 0; i < 4; ++i) {
            const int e4 = i * 256 + t;
            const float4 v = src[e4];
            const int e = e4 * 4;
            const int row = e >> 6, col = e & 63;
            uint2 ph;
            ph.x = (unsigned)f2bf(v.x) | ((unsigned)f2bf(v.y) << 16);
            ph.y = (unsigned)f2bf(v.z) | ((unsigned)f2bf(v.w) << 16);
            *(uint2*)&fijs[row * 68 + col] = ph;
        }
    }
    if (t < NK) nbs[t] = neighbors[(size_t)bn * NK + t];
    __syncthreads();                                            // bar1

    // Hoist Phase-B gather loads: latency hides under A1+A2.
    const float avc = a_c[(size_t)(b * NH + wave) * NN + n_];
    const float avn = a_n[(size_t)(b * NH + wave) * NN + nbs[lane]];
    const float pmk = pmask[(size_t)bn * NK + lane];

    // ---- Phase A1: W1 = ssp(f_ij @ wf1 + bf1), 2-term MFMA (wf1 hi+lo) ----
    f32x4 acc[4][2];
    {
        #pragma unroll
        for (int mf = 0; mf < 4; ++mf)
            #pragma unroll
            for (int nf2 = 0; nf2 < 2; ++nf2) acc[mf][nf2] = (f32x4)0.f;

        #pragma unroll
        for (int ks = 0; ks < 2; ++ks) {
            FragU b1h[2], b1l[2];
            #pragma unroll
            for (int nf2 = 0; nf2 < 2; ++nf2) {
                const int fi = ks * 8 + wave * 2 + nf2;
                b1h[nf2].u4 = *((const uint4*)wf1f + fi * 64 + lane);
                b1l[nf2].u4 = *((const uint4*)(wf1f + 8192) + fi * 64 + lane);
            }
            const int cb = ks * 32 + lq * 4;
            #pragma unroll
            for (int mf = 0; mf < 4; ++mf) {
                const int row = mf * 16 + lrow;
                FragU ah;
                {
                    const uint2 p0 = *(const uint2*)&fijs[row * 68 + cb];
                    const uint2 p1 = *(const uint2*)&fijs[row * 68 + cb + 16];
                    uint4 q; q.x = p0.x; q.y = p0.y; q.z = p1.x; q.w = p1.y; ah.u4 = q;
                }
                #pragma unroll
                for (int nf2 = 0; nf2 < 2; ++nf2) {
                    acc[mf][nf2] = __builtin_amdgcn_mfma_f32_16x16x32_bf16(ah.s8, b1h[nf2].s8, acc[mf][nf2], 0, 0, 0);
                    acc[mf][nf2] = __builtin_amdgcn_mfma_f32_16x16x32_bf16(ah.s8, b1l[nf2].s8, acc[mf][nf2], 0, 0, 0);
                }
            }
        }
    }
    __syncthreads();                                            // bar2 (fij reads done)
    {
        const float bia[2] = { bf1[wb + lrow], bf1[wb + 16 + lrow] };
        #pragma unroll
        for (int mf = 0; mf < 4; ++mf)
            #pragma unroll
            for (int nf2 = 0; nf2 < 2; ++nf2) {
                const int col = wb + nf2 * 16 + lrow;
                #pragma unroll
                for (int r = 0; r < 4; ++r) {
                    const int row = mf * 16 + lq * 4 + r;
                    W1[row * 132 + col] = f2bf(sspf(acc[mf][nf2][r] + bia[nf2]));
                }
            }
    }
    __syncthreads();                                            // bar3 (W1 written)

    // ---- Phase A2: W2 = W1 @ wf2 + bf2, 1-term MFMA (wf2 hi) ----
    {
        #pragma unroll
        for (int mf = 0; mf < 4; ++mf)
            #pragma unroll
            for (int nf2 = 0; nf2 < 2; ++nf2) acc[mf][nf2] = (f32x4)0.f;

        for (int ks = 0; ks < 4; ++ks) {
            FragU b2h[2];
            #pragma unroll
            for (int nf2 = 0; nf2 < 2; ++nf2) {
                const int fi = ks * 8 + wave * 2 + nf2;
                b2h[nf2].u4 = *((const uint4*)wf2f + fi * 64 + lane);
            }
            const int cb = ks * 32 + lq * 4;
            #pragma unroll
            for (int mf = 0; mf < 4; ++mf) {
                const int row = mf * 16 + lrow;
                FragU ah;
                {
                    const uint2 p0 = *(const uint2*)&W1[row * 132 + cb];
                    const uint2 p1 = *(const uint2*)&W1[row * 132 + cb + 16];
                    uint4 q; q.x = p0.x; q.y = p0.y; q.z = p1.x; q.w = p1.y; ah.u4 = q;
                }
                #pragma unroll
                for (int nf2 = 0; nf2 < 2; ++nf2)
                    acc[mf][nf2] = __builtin_amdgcn_mfma_f32_16x16x32_bf16(ah.s8, b2h[nf2].s8, acc[mf][nf2], 0, 0, 0);
            }
        }
    }
    __syncthreads();                                            // bar4 (W1 reads done)
    {
        const float bia[2] = { bf2v[wb + lrow], bf2v[wb + 16 + lrow] };
        #pragma unroll
        for (int mf = 0; mf < 4; ++mf)
            #pragma unroll
            for (int nf2 = 0; nf2 < 2; ++nf2) {
                const int col = wb + nf2 * 16 + lrow;
                #pragma unroll
                for (int r = 0; r < 4; ++r) {
                    const int row = mf * 16 + lq * 4 + r;
                    W2[row * 132 + col] = f2bf(acc[mf][nf2][r] + bia[nf2]);
                }
            }
    }

    // ---- Phase B: attention softmax (wave == head), mask folded into alpha ----
    {
        const float att = sspf(avc + avn);
        float m = att;
        #pragma unroll
        for (int off = 32; off > 0; off >>= 1) m = fmaxf(m, __shfl_xor(m, off, 64));
        const float e = __builtin_amdgcn_exp2f((att - m) * 1.44269504088896341f);
        float s = e;
        #pragma unroll
        for (int off = 32; off > 0; off >>= 1) s += __shfl_xor(s, off, 64);
        alpha[wave * 64 + lane] = (e / s) * pmk;
    }
    __syncthreads();                                            // bar5 (W2+alpha ready)

    // ---- Phase C: agg[f] = (1/H) sum_k W2[k][f] * sum_h alpha[h][k]*y[b,h,nb,f] ----
    {
        const int fq = (t & 31) * 4;
        const int kg = t >> 5;          // 0..7
        float4 accv; accv.x = accv.y = accv.z = accv.w = 0.f;
        const ushort_t* yb = y + (size_t)b * NH * NN * NF;
        #pragma unroll 2
        for (int kk = 0; kk < 8; ++kk) {
            const int k = kg * 8 + kk;
            const int nb = nbs[k];
            const ushort_t* yp = yb + (size_t)nb * NF + fq;
            const uint2 u0 = *(const uint2*)(yp);
            const uint2 u1 = *(const uint2*)(yp + (size_t)NN * NF);
            const uint2 u2 = *(const uint2*)(yp + 2 * (size_t)NN * NF);
            const uint2 u3 = *(const uint2*)(yp + 3 * (size_t)NN * NF);
            const float a0 = alpha[0 * 64 + k], a1 = alpha[1 * 64 + k];
            const float a2 = alpha[2 * 64 + k], a3 = alpha[3 * 64 + k];
            float4 s;
            s.x = fmaf(a3, bf2f((ushort_t)(u3.x & 0xffffu)),
                  fmaf(a2, bf2f((ushort_t)(u2.x & 0xffffu)),
                  fmaf(a1, bf2f((ushort_t)(u1.x & 0xffffu)),
                       a0 * bf2f((ushort_t)(u0.x & 0xffffu)))));
            s.y = fmaf(a3, bf2f((ushort_t)(u3.x >> 16)),
                  fmaf(a2, bf2f((ushort_t)(u2.x >> 16)),
                  fmaf(a1, bf2f((ushort_t)(u1.x >> 16)),
                       a0 * bf2f((ushort_t)(u0.x >> 16)))));
            s.z = fmaf(a3, bf2f((ushort_t)(u3.y & 0xffffu)),
                  fmaf(a2, bf2f((ushort_t)(u2.y & 0xffffu)),
                  fmaf(a1, bf2f((ushort_t)(u1.y & 0xffffu)),
                       a0 * bf2f((ushort_t)(u0.y & 0xffffu)))));
            s.w = fmaf(a3, bf2f((ushort_t)(u3.y >> 16)),
                  fmaf(a2, bf2f((ushort_t)(u2.y >> 16)),
                  fmaf(a1, bf2f((ushort_t)(u1.y >> 16)),
                       a0 * bf2f((ushort_t)(u0.y >> 16)))));
            const uint2 wv = *(const uint2*)&W2[k * 132 + fq];
            accv.x = fmaf(bf2f((ushort_t)(wv.x & 0xffffu)), s.x, accv.x);
            accv.y = fmaf(bf2f((ushort_t)(wv.x >> 16)),     s.y, accv.y);
            accv.z = fmaf(bf2f((ushort_t)(wv.y & 0xffffu)), s.z, accv.z);
            accv.w = fmaf(bf2f((ushort_t)(wv.y >> 16)),     s.w, accv.w);
        }
        *(float4*)&aggp[kg * 128 + fq] = accv;   // own region, no overlay hazard
    }
    __syncthreads();                                            // bar6 (aggp written)
    if (t < NF) {
        float s = 0.f;
        #pragma unroll
        for (int q = 0; q < 8; ++q) s += aggp[q * 128 + t];
        aggc[t] = s * 0.25f;   // / H
    }
    __syncthreads();                                            // bar7

    // ---- Phase D: out = ssp(agg @ w_outT + b_out), vectorized loads ----
    if (t < NO) {
        float z = b_out[t];
        const float4* wr = (const float4*)(w_outT + (size_t)t * NF);
        #pragma unroll 8
        for (int q = 0; q < NF / 4; ++q) {
            const float4 w = wr[q];
            const float4 a = *(const float4*)&aggc[q * 4];
            z = fmaf(a.x, w.x, fmaf(a.y, w.y, fmaf(a.z, w.z, fmaf(a.w, w.w, z))));
        }
        outp[(size_t)bn * NO + t] = sspf(z);
    }
}

extern "C" void kernel_launch(void* const* d_in, const int* in_sizes, int n_in,
                              void* d_out, int out_size, void* d_ws, size_t ws_size,
                              hipStream_t stream) {
    const float* x      = (const float*)d_in[0];
    // d_in[1] = r_ij (unused by reference)
    const int*   nbr    = (const int*)d_in[2];
    const float* pmask  = (const float*)d_in[3];
    const float* f_ij   = (const float*)d_in[4];
    const float* w_in2f = (const float*)d_in[5];
    const float* w_att  = (const float*)d_in[6];
    const float* wf1    = (const float*)d_in[7];
    const float* bf1    = (const float*)d_in[8];
    const float* wf2    = (const float*)d_in[9];
    const float* bf2v   = (const float*)d_in[10];
    const float* w_out  = (const float*)d_in[11];
    const float* b_out  = (const float*)d_in[12];

    // ws layout (total ~2.22 MB):
    //   yb16  [B][H][N][F] bf16 : 2 MB
    //   a_c   [B][H][N] f32     : 32 KB
    //   a_n   [B][H][N] f32     : 32 KB
    //   wf1f  hi+lo bf16 tables : 32 KB
    //   wf2f  hi+lo bf16 tables : 64 KB
    //   w_outT [O][F] f32       : 64 KB
    ushort_t* yb16  = (ushort_t*)d_ws;
    float*    a_c   = (float*)(yb16 + (size_t)NB * NH * NN * NF);
    float*    a_n   = a_c + (size_t)NB * NH * NN;
    ushort_t* wf1f  = (ushort_t*)(a_n + (size_t)NB * NH * NN);
    ushort_t* wf2f  = wf1f + 16384;
    float*    w_outT = (float*)(wf2f + 32768);

    float* outp = (float*)d_out;

    k_projprep<<<1024 + 28, 256, 0, stream>>>(
        x, w_in2f, w_att, wf1, wf2, w_out, yb16, a_c, a_n, wf1f, wf2f, w_outT);
    k_main<<<NB * NN, 256, 0, stream>>>(nbr, pmask, f_ij, bf1, bf2v,
                                        w_outT, b_out, yb16, a_c, a_n, wf1f, wf2f, outp);
}

// Round 19
// 51.669 us; speedup vs baseline: 1.1456x; 1.0111x over previous
//
#include <hip/hip_runtime.h>

#define NB 2
#define NN 1024
#define NK 64
#define NG 64
#define NF 128
#define NH 4
#define NO 128

typedef unsigned short ushort_t;
typedef __attribute__((ext_vector_type(8))) short short8v;
typedef __attribute__((ext_vector_type(4))) float f32x4;

union FragU { uint4 u4; short8v s8; };

__device__ __forceinline__ float bf2f(ushort_t u) {
    union { unsigned int i; float f; } v; v.i = ((unsigned int)u) << 16; return v.f;
}
__device__ __forceinline__ ushort_t f2bf(float f) {
    unsigned int u = __float_as_uint(f);
    unsigned int r = 0x7fffu + ((u >> 16) & 1u);
    return (ushort_t)((u + r) >> 16);
}
// shifted softplus via hardware exp2/log2:
// ssp(x) = max(x,0) + ln2*log2(1 + 2^(-|x|*log2e)) - ln2; abs err ~1e-7.
__device__ __forceinline__ float sspf(float x) {
    const float u = __builtin_amdgcn_exp2f(-fabsf(x) * 1.44269504088896341f);
    return fmaxf(x, 0.f) + fmaf(0.69314718055994531f,
                                __builtin_amdgcn_logf(1.f + u),
                                -0.69314718055994531f);
}

// ---------------------------------------------------------------------------
// Kernel 1 (round 18, unchanged): head-split projection for 4x parallelism.
// blocks [0,1024): proj — block (g,h) = (idx>>2, idx&3) computes y rows
//   [8g,8g+8) for head h.  blocks [1024,1052): weight prep.
// frag table layout: table[(fi*64+lane)*8+j], fi = ks*8+nf; element j maps to
// k = ks*32 + ((lane>>4)&3)*4 + (j&3) + 16*(j>>2), n = nf*16 + (lane&15).
// ---------------------------------------------------------------------------
__global__ __launch_bounds__(256) void k_projprep(
    const float* __restrict__ x,       // [B][N][F]
    const float* __restrict__ w_in2f,  // [H][F][F]
    const float* __restrict__ w_att,   // [H][2F]
    const float* __restrict__ wf1, const float* __restrict__ wf2,
    const float* __restrict__ w_out,
    ushort_t* __restrict__ y,          // [B][H][N][F] bf16
    float* __restrict__ a_c,           // [B][H][N]
    float* __restrict__ a_n,           // [B][H][N]
    ushort_t* __restrict__ wf1f, ushort_t* __restrict__ wf2f,
    float* __restrict__ w_outT)
{
    const int t = threadIdx.x;
    __shared__ float xs[8][NF];        // 4 KB
    __shared__ float ys[8][NF];        // 4 KB (stride-1 dot reads, no conflict)

    if (blockIdx.x >= 1024) {
        // ---- prep path ----
        int s = (blockIdx.x - 1024) * 256 + t;
        if (s >= 7168) return;
        if (s >= 3072) {
            const int s2 = s - 3072;           // [0,4096)
            const int o = s2 >> 5, fb = s2 & 31;
            #pragma unroll
            for (int j = 0; j < 4; ++j)
                w_outT[(size_t)o * NF + fb * 4 + j] = w_out[(size_t)(fb * 4 + j) * NO + o];
            return;
        }
        const float* W; ushort_t* out; int loOff;
        if (s < 1024) { W = wf1; out = wf1f; loOff = 8192; }
        else          { s -= 1024; W = wf2; out = wf2f; loOff = 16384; }
        const int fi = s >> 6, lane = s & 63;
        const int ks = fi >> 3, nf = fi & 7;
        const int n = nf * 16 + (lane & 15);
        const int kb = ks * 32 + ((lane >> 4) & 3) * 4;
        #pragma unroll
        for (int j = 0; j < 8; ++j) {
            const int k = kb + (j & 3) + ((j >> 2) << 4);
            const float v = W[(size_t)k * NF + n];
            const ushort_t hb = f2bf(v);
            out[(size_t)(fi * 64 + lane) * 8 + j] = hb;
            out[(size_t)loOff + (fi * 64 + lane) * 8 + j] = f2bf(v - bf2f(hb));
        }
        return;
    }

    // ---- projection path: 8 rows x 1 head per block ----
    const int g  = blockIdx.x >> 2;
    const int h  = blockIdx.x & 3;
    const int bn0 = g * 8;
    {
        const float4* src = (const float4*)(x + (size_t)bn0 * NF);
        float4* dst = (float4*)(&xs[0][0]);
        dst[t] = src[t];               // 256 float4 = 8 rows
    }
    __syncthreads();

    const int f0 = t & 127;
    const int rp = t >> 7;             // 0..1 -> rows [4rp, 4rp+4)
    const float* wp = w_in2f + (size_t)h * NF * NF + f0;
    float acc[4];
    #pragma unroll
    for (int j = 0; j < 4; ++j) acc[j] = 0.f;

    for (int i0 = 0; i0 < NF; i0 += 4) {
        float4 xv[4];
        #pragma unroll
        for (int j = 0; j < 4; ++j) xv[j] = *(const float4*)&xs[rp * 4 + j][i0];
        #pragma unroll
        for (int ii = 0; ii < 4; ++ii) {
            const float w = wp[(size_t)(i0 + ii) * NF];
            #pragma unroll
            for (int j = 0; j < 4; ++j)
                acc[j] = fmaf((&xv[j].x)[ii], w, acc[j]);
        }
    }
    #pragma unroll
    for (int j = 0; j < 4; ++j) {
        const int bn = bn0 + rp * 4 + j;
        const int b = bn >> 10, nn = bn & (NN - 1);
        y[((size_t)(b * NH + h) * NN + nn) * NF + f0] = f2bf(acc[j]);
        ys[rp * 4 + j][f0] = acc[j];
    }
    __syncthreads();

    // attention dots: row r handled by 32 lanes, stride-1 f reads
    {
        const int r = t >> 5, q = t & 31;
        float pc = 0.f, pn = 0.f;
        #pragma unroll
        for (int j = 0; j < 4; ++j) {
            const int f = q + 32 * j;
            const float yv = ys[r][f];
            pc = fmaf(yv, w_att[h * 2 * NF + f], pc);
            pn = fmaf(yv, w_att[h * 2 * NF + NF + f], pn);
        }
        #pragma unroll
        for (int off = 1; off < 32; off <<= 1) {
            pc += __shfl_xor(pc, off, 32);
            pn += __shfl_xor(pn, off, 32);
        }
        if (q == 0) {
            const int bn = bn0 + r;
            const int b = bn >> 10, nn = bn & (NN - 1);
            a_c[(size_t)(b * NH + h) * NN + nn] = pc;
            a_n[(size_t)(b * NH + h) * NN + nn] = pn;
        }
    }
}

// ---------------------------------------------------------------------------
// Kernel 2 (round 19): round-16 dataflow; launch_bounds (256,6)->(256,5)
// gives the scheduler 102-reg headroom (was 85, compiler pinned to 40 VGPR),
// enabling Phase-C unroll-4 load batching (16 in-flight gathers) without
// spill. Occupancy 6->5 blocks/CU (measured time-neutral in the 4-6 range).
// TRIPWIRE: WRITE_SIZE >> 1 MB = spill = revert to round-18 config as final.
// LDS map (22784 B):
//   R1 [0     ..16896)  fij [64][68] bf16 -> W1 [64][132] -> W2 [64][132]
//   R2 [16896 ..20992)  aggp [8][128] f32
//      [20992 ..21504)  aggc [128] f32
//   R3 [21504 ..22528)  alpha [4][64] f32
//      [22528 ..22784)  nbs [64] int
// ---------------------------------------------------------------------------
__global__ __launch_bounds__(256, 5) void k_main(
    const int*      __restrict__ neighbors, // [B][N][K]
    const float*    __restrict__ pmask,     // [B][N][K]
    const float*    __restrict__ f_ij,      // [B][N][K][G]
    const float*    __restrict__ bf1,       // [F]
    const float*    __restrict__ bf2v,      // [F]
    const float*    __restrict__ w_outT,    // [O][F] transposed
    const float*    __restrict__ b_out,     // [O]
    const ushort_t* __restrict__ y,         // [B][H][N][F] bf16
    const float*    __restrict__ a_c,       // [B][H][N]
    const float*    __restrict__ a_n,       // [B][H][N]
    const ushort_t* __restrict__ wf1f,      // frag table hi/lo
    const ushort_t* __restrict__ wf2f,      // frag table hi
    float*          __restrict__ outp)      // [B][N][O]
{
    const int bn = blockIdx.x;
    const int b = bn >> 10, n_ = bn & (NN - 1);
    const int t = threadIdx.x;

    __shared__ __align__(16) char smem[22784];
    ushort_t* fijs = (ushort_t*)(smem);           // [64][68] bf16 (rounded)
    ushort_t* W1   = (ushort_t*)(smem);           // [64][132] overlay (after bar2)
    ushort_t* W2   = (ushort_t*)(smem);           // [64][132] overlay (after bar4)
    float*    aggp = (float*)(smem + 16896);      // [8][128]
    float*    aggc = (float*)(smem + 20992);      // [128]
    float*    alpha = (float*)(smem + 21504);     // [4][64]
    int*      nbs   = (int*)(smem + 22528);       // [64]

    const int wave = t >> 6, lane = t & 63;
    const int lrow = lane & 15;          // A-row / B-col / C-col within frag
    const int lq   = (lane >> 4) & 3;    // quarter
    const int wb   = wave * 32;          // this wave's N-column base

    // ---- stage f_ij (fp32 global, coalesced) -> rounded bf16 LDS ----
    {
        const float4* src = (const float4*)(f_ij + (size_t)bn * NK * NG);
        #pragma unroll
        for (int i = 0; i < 4; ++i) {
            const int e4 = i * 256 + t;
            const float4 v = src[e4];
            const int e = e4 * 4;
            const int row = e >> 6, col = e & 63;
            uint2 ph;
            ph.x = (unsigned)f2bf(v.x) | ((unsigned)f2bf(v.y) << 16);
            ph.y = (unsigned)f2bf(v.z) | ((unsigned)f2bf(v.w) << 16);
            *(uint2*)&fijs[row * 68 + col] = ph;
        }
    }
    if (t < NK) nbs[t] = neighbors[(size_t)bn * NK + t];
    __syncthreads();                                            // bar1

    // Hoist Phase-B gather loads: latency hides under A1+A2.
    const float avc = a_c[(size_t)(b * NH + wave) * NN + n_];
    const float avn = a_n[(size_t)(b * NH + wave) * NN + nbs[lane]];
    const float pmk = pmask[(size_t)bn * NK + lane];

    // ---- Phase A1: W1 = ssp(f_ij @ wf1 + bf1), 2-term MFMA (wf1 hi+lo) ----
    f32x4 acc[4][2];
    {
        #pragma unroll
        for (int mf = 0; mf < 4; ++mf)
            #pragma unroll
            for (int nf2 = 0; nf2 < 2; ++nf2) acc[mf][nf2] = (f32x4)0.f;

        #pragma unroll
        for (int ks = 0; ks < 2; ++ks) {
            FragU b1h[2], b1l[2];
            #pragma unroll
            for (int nf2 = 0; nf2 < 2; ++nf2) {
                const int fi = ks * 8 + wave * 2 + nf2;
                b1h[nf2].u4 = *((const uint4*)wf1f + fi * 64 + lane);
                b1l[nf2].u4 = *((const uint4*)(wf1f + 8192) + fi * 64 + lane);
            }
            const int cb = ks * 32 + lq * 4;
            #pragma unroll
            for (int mf = 0; mf < 4; ++mf) {
                const int row = mf * 16 + lrow;
                FragU ah;
                {
                    const uint2 p0 = *(const uint2*)&fijs[row * 68 + cb];
                    const uint2 p1 = *(const uint2*)&fijs[row * 68 + cb + 16];
                    uint4 q; q.x = p0.x; q.y = p0.y; q.z = p1.x; q.w = p1.y; ah.u4 = q;
                }
                #pragma unroll
                for (int nf2 = 0; nf2 < 2; ++nf2) {
                    acc[mf][nf2] = __builtin_amdgcn_mfma_f32_16x16x32_bf16(ah.s8, b1h[nf2].s8, acc[mf][nf2], 0, 0, 0);
                    acc[mf][nf2] = __builtin_amdgcn_mfma_f32_16x16x32_bf16(ah.s8, b1l[nf2].s8, acc[mf][nf2], 0, 0, 0);
                }
            }
        }
    }
    __syncthreads();                                            // bar2 (fij reads done)
    {
        const float bia[2] = { bf1[wb + lrow], bf1[wb + 16 + lrow] };
        #pragma unroll
        for (int mf = 0; mf < 4; ++mf)
            #pragma unroll
            for (int nf2 = 0; nf2 < 2; ++nf2) {
                const int col = wb + nf2 * 16 + lrow;
                #pragma unroll
                for (int r = 0; r < 4; ++r) {
                    const int row = mf * 16 + lq * 4 + r;
                    W1[row * 132 + col] = f2bf(sspf(acc[mf][nf2][r] + bia[nf2]));
                }
            }
    }
    __syncthreads();                                            // bar3 (W1 written)

    // ---- Phase A2: W2 = W1 @ wf2 + bf2, 1-term MFMA (wf2 hi) ----
    {
        #pragma unroll
        for (int mf = 0; mf < 4; ++mf)
            #pragma unroll
            for (int nf2 = 0; nf2 < 2; ++nf2) acc[mf][nf2] = (f32x4)0.f;

        for (int ks = 0; ks < 4; ++ks) {
            FragU b2h[2];
            #pragma unroll
            for (int nf2 = 0; nf2 < 2; ++nf2) {
                const int fi = ks * 8 + wave * 2 + nf2;
                b2h[nf2].u4 = *((const uint4*)wf2f + fi * 64 + lane);
            }
            const int cb = ks * 32 + lq * 4;
            #pragma unroll
            for (int mf = 0; mf < 4; ++mf) {
                const int row = mf * 16 + lrow;
                FragU ah;
                {
                    const uint2 p0 = *(const uint2*)&W1[row * 132 + cb];
                    const uint2 p1 = *(const uint2*)&W1[row * 132 + cb + 16];
                    uint4 q; q.x = p0.x; q.y = p0.y; q.z = p1.x; q.w = p1.y; ah.u4 = q;
                }
                #pragma unroll
                for (int nf2 = 0; nf2 < 2; ++nf2)
                    acc[mf][nf2] = __builtin_amdgcn_mfma_f32_16x16x32_bf16(ah.s8, b2h[nf2].s8, acc[mf][nf2], 0, 0, 0);
            }
        }
    }
    __syncthreads();                                            // bar4 (W1 reads done)
    {
        const float bia[2] = { bf2v[wb + lrow], bf2v[wb + 16 + lrow] };
        #pragma unroll
        for (int mf = 0; mf < 4; ++mf)
            #pragma unroll
            for (int nf2 = 0; nf2 < 2; ++nf2) {
                const int col = wb + nf2 * 16 + lrow;
                #pragma unroll
                for (int r = 0; r < 4; ++r) {
                    const int row = mf * 16 + lq * 4 + r;
                    W2[row * 132 + col] = f2bf(acc[mf][nf2][r] + bia[nf2]);
                }
            }
    }

    // ---- Phase B: attention softmax (wave == head), mask folded into alpha ----
    {
        const float att = sspf(avc + avn);
        float m = att;
        #pragma unroll
        for (int off = 32; off > 0; off >>= 1) m = fmaxf(m, __shfl_xor(m, off, 64));
        const float e = __builtin_amdgcn_exp2f((att - m) * 1.44269504088896341f);
        float s = e;
        #pragma unroll
        for (int off = 32; off > 0; off >>= 1) s += __shfl_xor(s, off, 64);
        alpha[wave * 64 + lane] = (e / s) * pmk;
    }
    __syncthreads();                                            // bar5 (W2+alpha ready)

    // ---- Phase C: agg[f] = (1/H) sum_k W2[k][f] * sum_h alpha[h][k]*y[b,h,nb,f] ----
    {
        const int fq = (t & 31) * 4;
        const int kg = t >> 5;          // 0..7
        float4 accv; accv.x = accv.y = accv.z = accv.w = 0.f;
        const ushort_t* yb = y + (size_t)b * NH * NN * NF;
        #pragma unroll 4
        for (int kk = 0; kk < 8; ++kk) {
            const int k = kg * 8 + kk;
            const int nb = nbs[k];
            const ushort_t* yp = yb + (size_t)nb * NF + fq;
            const uint2 u0 = *(const uint2*)(yp);
            const uint2 u1 = *(const uint2*)(yp + (size_t)NN * NF);
            const uint2 u2 = *(const uint2*)(yp + 2 * (size_t)NN * NF);
            const uint2 u3 = *(const uint2*)(yp + 3 * (size_t)NN * NF);
            const float a0 = alpha[0 * 64 + k], a1 = alpha[1 * 64 + k];
            const float a2 = alpha[2 * 64 + k], a3 = alpha[3 * 64 + k];
            float4 s;
            s.x = fmaf(a3, bf2f((ushort_t)(u3.x & 0xffffu)),
                  fmaf(a2, bf2f((ushort_t)(u2.x & 0xffffu)),
                  fmaf(a1, bf2f((ushort_t)(u1.x & 0xffffu)),
                       a0 * bf2f((ushort_t)(u0.x & 0xffffu)))));
            s.y = fmaf(a3, bf2f((ushort_t)(u3.x >> 16)),
                  fmaf(a2, bf2f((ushort_t)(u2.x >> 16)),
                  fmaf(a1, bf2f((ushort_t)(u1.x >> 16)),
                       a0 * bf2f((ushort_t)(u0.x >> 16)))));
            s.z = fmaf(a3, bf2f((ushort_t)(u3.y & 0xffffu)),
                  fmaf(a2, bf2f((ushort_t)(u2.y & 0xffffu)),
                  fmaf(a1, bf2f((ushort_t)(u1.y & 0xffffu)),
                       a0 * bf2f((ushort_t)(u0.y & 0xffffu)))));
            s.w = fmaf(a3, bf2f((ushort_t)(u3.y >> 16)),
                  fmaf(a2, bf2f((ushort_t)(u2.y >> 16)),
                  fmaf(a1, bf2f((ushort_t)(u1.y >> 16)),
                       a0 * bf2f((ushort_t)(u0.y >> 16)))));
            const uint2 wv = *(const uint2*)&W2[k * 132 + fq];
            accv.x = fmaf(bf2f((ushort_t)(wv.x & 0xffffu)), s.x, accv.x);
            accv.y = fmaf(bf2f((ushort_t)(wv.x >> 16)),     s.y, accv.y);
            accv.z = fmaf(bf2f((ushort_t)(wv.y & 0xffffu)), s.z, accv.z);
            accv.w = fmaf(bf2f((ushort_t)(wv.y >> 16)),     s.w, accv.w);
        }
        *(float4*)&aggp[kg * 128 + fq] = accv;   // own region, no overlay hazard
    }
    __syncthreads();                                            // bar6 (aggp written)
    if (t < NF) {
        float s = 0.f;
        #pragma unroll
        for (int q = 0; q < 8; ++q) s += aggp[q * 128 + t];
        aggc[t] = s * 0.25f;   // / H
    }
    __syncthreads();                                            // bar7

    // ---- Phase D: out = ssp(agg @ w_outT + b_out), vectorized loads ----
    if (t < NO) {
        float z = b_out[t];
        const float4* wr = (const float4*)(w_outT + (size_t)t * NF);
        #pragma unroll 8
        for (int q = 0; q < NF / 4; ++q) {
            const float4 w = wr[q];
            const float4 a = *(const float4*)&aggc[q * 4];
            z = fmaf(a.x, w.x, fmaf(a.y, w.y, fmaf(a.z, w.z, fmaf(a.w, w.w, z))));
        }
        outp[(size_t)bn * NO + t] = sspf(z);
    }
}

extern "C" void kernel_launch(void* const* d_in, const int* in_sizes, int n_in,
                              void* d_out, int out_size, void* d_ws, size_t ws_size,
                              hipStream_t stream) {
    const float* x      = (const float*)d_in[0];
    // d_in[1] = r_ij (unused by reference)
    const int*   nbr    = (const int*)d_in[2];
    const float* pmask  = (const float*)d_in[3];
    const float* f_ij   = (const float*)d_in[4];
    const float* w_in2f = (const float*)d_in[5];
    const float* w_att  = (const float*)d_in[6];
    const float* wf1    = (const float*)d_in[7];
    const float* bf1    = (const float*)d_in[8];
    const float* wf2    = (const float*)d_in[9];
    const float* bf2v   = (const float*)d_in[10];
    const float* w_out  = (const float*)d_in[11];
    const float* b_out  = (const float*)d_in[12];

    // ws layout (total ~2.22 MB):
    //   yb16  [B][H][N][F] bf16 : 2 MB
    //   a_c   [B][H][N] f32     : 32 KB
    //   a_n   [B][H][N] f32     : 32 KB
    //   wf1f  hi+lo bf16 tables : 32 KB
    //   wf2f  hi+lo bf16 tables : 64 KB
    //   w_outT [O][F] f32       : 64 KB
    ushort_t* yb16  = (ushort_t*)d_ws;
    float*    a_c   = (float*)(yb16 + (size_t)NB * NH * NN * NF);
    float*    a_n   = a_c + (size_t)NB * NH * NN;
    ushort_t* wf1f  = (ushort_t*)(a_n + (size_t)NB * NH * NN);
    ushort_t* wf2f  = wf1f + 16384;
    float*    w_outT = (float*)(wf2f + 32768);

    float* outp = (float*)d_out;

    k_projprep<<<1024 + 28, 256, 0, stream>>>(
        x, w_in2f, w_att, wf1, wf2, w_out, yb16, a_c, a_n, wf1f, wf2f, w_outT);
    k_main<<<NB * NN, 256, 0, stream>>>(nbr, pmask, f_ij, bf1, bf2v,
                                        w_outT, b_out, yb16, a_c, a_n, wf1f, wf2f, outp);
}